// Round 1
// baseline (1160.777 us; speedup 1.0000x reference)
//
#include <hip/hip_runtime.h>
#include <hip/hip_bf16.h>

#define N_NODES 50000
#define N_EDGES 800000
#define F 128
#define BN_EPS 1e-5f
#define SLOPE 0.01f

// ---------------- CSR build (once per call, reused across 4 layers) ----------------

__global__ void hist_kernel(const int* __restrict__ dst, int* __restrict__ deg) {
    int e = blockIdx.x * blockDim.x + threadIdx.x;
    if (e < N_EDGES) atomicAdd(&deg[dst[e]], 1);
}

// single-block exclusive scan of deg -> row_off, plus inv_deg
__global__ __launch_bounds__(1024) void scan_kernel(const int* __restrict__ deg,
                                                    int* __restrict__ row_off,
                                                    float* __restrict__ inv_deg) {
    __shared__ int part[1024];
    const int t = threadIdx.x;
    const int CH = (N_NODES + 1023) / 1024;  // 49
    int beg = t * CH;
    int end = beg + CH; if (end > N_NODES) end = N_NODES;
    if (beg > N_NODES) beg = N_NODES;
    int s = 0;
    for (int i = beg; i < end; ++i) s += deg[i];
    part[t] = s;
    const int own = s;
    __syncthreads();
    // Hillis-Steele inclusive scan over 1024 partials
    for (int off = 1; off < 1024; off <<= 1) {
        int v = 0;
        if (t >= off) v = part[t - off];
        __syncthreads();
        part[t] += v;
        __syncthreads();
    }
    int run = part[t] - own;  // exclusive prefix of this chunk
    for (int i = beg; i < end; ++i) {
        row_off[i] = run;
        int d = deg[i];
        inv_deg[i] = (d > 0) ? (1.0f / (float)d) : 0.0f;
        run += d;
    }
    if (t == 1023) row_off[N_NODES] = part[1023];
}

__global__ void fill_kernel(const int* __restrict__ src, const int* __restrict__ dst,
                            const int* __restrict__ row_off, int* __restrict__ cursor,
                            int* __restrict__ csr_src) {
    int e = blockIdx.x * blockDim.x + threadIdx.x;
    if (e < N_EDGES) {
        int d = dst[e];
        int pos = atomicAdd(&cursor[d], 1);
        csr_src[row_off[d] + pos] = src[e];
    }
}

// ---------------- per-layer kernels ----------------

// one wave (64 lanes) per destination node; lane holds 2 features (float2)
__global__ __launch_bounds__(256) void agg_kernel(const float* __restrict__ h,
                                                  const int* __restrict__ row_off,
                                                  const int* __restrict__ csr_src,
                                                  const float* __restrict__ inv_deg,
                                                  float* __restrict__ agg) {
    int node = (int)((blockIdx.x * (unsigned)blockDim.x + threadIdx.x) >> 6);
    int lane = threadIdx.x & 63;
    if (node >= N_NODES) return;
    int beg = row_off[node], end = row_off[node + 1];
    float ax = 0.f, ay = 0.f;
    for (int e = beg; e < end; ++e) {
        int s = csr_src[e];
        float2 v = ((const float2*)(h + (long)s * F))[lane];
        ax += v.x;
        ay += v.y;
    }
    float inv = inv_deg[node];
    ((float2*)(agg + (long)node * F))[lane] = make_float2(ax * inv, ay * inv);
}

__device__ __forceinline__ void fma4(float4& acc, const float4 a,
                                     const float4 w0, const float4 w1,
                                     const float4 w2, const float4 w3) {
    acc.x += a.x * w0.x + a.y * w1.x + a.z * w2.x + a.w * w3.x;
    acc.y += a.x * w0.y + a.y * w1.y + a.z * w2.y + a.w * w3.y;
    acc.z += a.x * w0.z + a.y * w1.z + a.z * w2.z + a.w * w3.z;
    acc.w += a.x * w0.w + a.y * w1.w + a.z * w2.w + a.w * w3.w;
}

// hout = leaky( agg@Wl + bl + hin@Wr ), plus per-column sum / sumsq for BN.
// block: 256 threads, tile 64 rows x 128 cols; thread: 8 rows x 4 cols.
__global__ __launch_bounds__(256) void gemm_kernel(const float* __restrict__ agg,
                                                   const float* __restrict__ hin,
                                                   const float* __restrict__ Wl,
                                                   const float* __restrict__ bl,
                                                   const float* __restrict__ Wr,
                                                   float* __restrict__ hout,
                                                   float* __restrict__ sum,
                                                   float* __restrict__ sumsq) {
    __shared__ float ldsA[64 * 36];  // [row][36], float4 row stride 9
    __shared__ float ldsH[64 * 36];
    const int tid = threadIdx.x;
    const int r0 = blockIdx.x * 64;
    const int cg = tid & 31;   // col group -> j0 = cg*4
    const int rg = tid >> 5;   // 0..7 -> rows rg*8 .. rg*8+7
    const int j0 = cg * 4;

    float4 acc[8];
#pragma unroll
    for (int r = 0; r < 8; ++r) acc[r] = make_float4(0.f, 0.f, 0.f, 0.f);

    const int lrow = tid >> 2;  // 0..63
    const int lq = tid & 3;     // 0..3

    for (int kk = 0; kk < F; kk += 32) {
        __syncthreads();
        {
            const int gr = r0 + lrow;
            float4 za = make_float4(0,0,0,0), za2 = za, zh = za, zh2 = za;
            if (gr < N_NODES) {
                const float4* ga = (const float4*)(agg + (long)gr * F + kk);
                const float4* gh = (const float4*)(hin + (long)gr * F + kk);
                za = ga[lq];  za2 = ga[lq + 4];
                zh = gh[lq];  zh2 = gh[lq + 4];
            }
            ((float4*)ldsA)[lrow * 9 + lq] = za;
            ((float4*)ldsA)[lrow * 9 + lq + 4] = za2;
            ((float4*)ldsH)[lrow * 9 + lq] = zh;
            ((float4*)ldsH)[lrow * 9 + lq + 4] = zh2;
        }
        __syncthreads();
#pragma unroll
        for (int k4 = 0; k4 < 8; ++k4) {
            float4 wl[4], wr[4];
#pragma unroll
            for (int kq = 0; kq < 4; ++kq) {
                const int k = kk + k4 * 4 + kq;
                wl[kq] = *(const float4*)(Wl + (long)k * F + j0);
                wr[kq] = *(const float4*)(Wr + (long)k * F + j0);
            }
#pragma unroll
            for (int r = 0; r < 8; ++r) {
                const int row = rg * 8 + r;
                float4 a4 = ((const float4*)ldsA)[row * 9 + k4];
                float4 h4 = ((const float4*)ldsH)[row * 9 + k4];
                fma4(acc[r], a4, wl[0], wl[1], wl[2], wl[3]);
                fma4(acc[r], h4, wr[0], wr[1], wr[2], wr[3]);
            }
        }
    }

    // epilogue: bias + leaky + store + per-thread column partials
    const float4 b4 = *(const float4*)(bl + j0);
    float4 cs = make_float4(0.f, 0.f, 0.f, 0.f), cq = cs;
#pragma unroll
    for (int r = 0; r < 8; ++r) {
        const int grow = r0 + rg * 8 + r;
        if (grow < N_NODES) {
            float4 v = acc[r];
            v.x += b4.x; v.y += b4.y; v.z += b4.z; v.w += b4.w;
            v.x = (v.x >= 0.f) ? v.x : SLOPE * v.x;
            v.y = (v.y >= 0.f) ? v.y : SLOPE * v.y;
            v.z = (v.z >= 0.f) ? v.z : SLOPE * v.z;
            v.w = (v.w >= 0.f) ? v.w : SLOPE * v.w;
            *(float4*)(hout + (long)grow * F + j0) = v;
            cs.x += v.x; cs.y += v.y; cs.z += v.z; cs.w += v.w;
            cq.x += v.x * v.x; cq.y += v.y * v.y; cq.z += v.z * v.z; cq.w += v.w * v.w;
        }
    }
    // block reduce across the 8 row-groups, then one atomic per column
    __syncthreads();
    ((float4*)ldsA)[rg * 32 + cg] = cs;  // [8][128]
    ((float4*)ldsH)[rg * 32 + cg] = cq;
    __syncthreads();
    if (tid < F) {
        float s = 0.f, q = 0.f;
#pragma unroll
        for (int g = 0; g < 8; ++g) {
            s += ldsA[g * 128 + tid];
            q += ldsH[g * 128 + tid];
        }
        atomicAdd(&sum[tid], s);
        atomicAdd(&sumsq[tid], q);
    }
}

__global__ void bn_prep(const float* __restrict__ sum, const float* __restrict__ sumsq,
                        const float* __restrict__ gamma, const float* __restrict__ beta,
                        float* __restrict__ scale, float* __restrict__ shift) {
    int j = threadIdx.x;
    if (j < F) {
        const float inv_n = 1.0f / (float)N_NODES;
        float mu = sum[j] * inv_n;
        float var = sumsq[j] * inv_n - mu * mu;
        float scl = gamma[j] * rsqrtf(var + BN_EPS);
        scale[j] = scl;
        shift[j] = beta[j] - mu * scl;
    }
}

__global__ __launch_bounds__(256) void bn_apply(float* __restrict__ h,
                                                const float* __restrict__ scale,
                                                const float* __restrict__ shift) {
    long i = (long)blockIdx.x * blockDim.x + threadIdx.x;  // float4 index
    if (i >= (long)N_NODES * (F / 4)) return;
    const int c4 = (int)(i & 31);
    float4 v = ((float4*)h)[i];
    const float4 sc = ((const float4*)scale)[c4];
    const float4 sh = ((const float4*)shift)[c4];
    v.x = v.x * sc.x + sh.x;
    v.y = v.y * sc.y + sh.y;
    v.z = v.z * sc.z + sh.z;
    v.w = v.w * sc.w + sh.w;
    ((float4*)h)[i] = v;
}

// ---------------- launch ----------------

extern "C" void kernel_launch(void* const* d_in, const int* in_sizes, int n_in,
                              void* d_out, int out_size, void* d_ws, size_t ws_size,
                              hipStream_t stream) {
    const float* x     = (const float*)d_in[0];
    const int*   ei    = (const int*)d_in[1];
    const float* Wl    = (const float*)d_in[2];
    const float* bl    = (const float*)d_in[3];
    const float* Wr    = (const float*)d_in[4];
    const float* gamma = (const float*)d_in[5];
    const float* beta  = (const float*)d_in[6];
    float* out = (float*)d_out;

    const int* src = ei;            // edge_index[0]
    const int* dst = ei + N_EDGES;  // edge_index[1]

    char* w = (char*)d_ws;
    auto alloc = [&](size_t bytes) -> char* {
        char* p = w;
        w += (bytes + 255) & ~(size_t)255;
        return p;
    };
    float* bufA    = (float*)alloc((size_t)N_NODES * F * 4);
    float* aggb    = (float*)alloc((size_t)N_NODES * F * 4);
    int*   deg     = (int*)alloc((size_t)N_NODES * 4);
    int*   row_off = (int*)alloc((size_t)(N_NODES + 1) * 4);
    int*   cursor  = (int*)alloc((size_t)N_NODES * 4);
    int*   csr_src = (int*)alloc((size_t)N_EDGES * 4);
    float* inv_deg = (float*)alloc((size_t)N_NODES * 4);
    float* sum     = (float*)alloc(F * 4);
    float* sumsq   = (float*)alloc(F * 4);
    float* scale   = (float*)alloc(F * 4);
    float* shift   = (float*)alloc(F * 4);

    hipMemsetAsync(deg, 0, (size_t)N_NODES * 4, stream);
    hipMemsetAsync(cursor, 0, (size_t)N_NODES * 4, stream);

    hist_kernel<<<(N_EDGES + 255) / 256, 256, 0, stream>>>(dst, deg);
    scan_kernel<<<1, 1024, 0, stream>>>(deg, row_off, inv_deg);
    fill_kernel<<<(N_EDGES + 255) / 256, 256, 0, stream>>>(src, dst, row_off, cursor, csr_src);

    const float* hin = x;
    for (int i = 0; i < 4; ++i) {
        // ping-pong: L0 -> bufA, L1 -> d_out, L2 -> bufA, L3 -> d_out
        float* hout = (i & 1) ? out : bufA;

        agg_kernel<<<(N_NODES + 3) / 4, 256, 0, stream>>>(hin, row_off, csr_src, inv_deg, aggb);

        hipMemsetAsync(sum, 0, F * 4, stream);
        hipMemsetAsync(sumsq, 0, F * 4, stream);

        gemm_kernel<<<(N_NODES + 63) / 64, 256, 0, stream>>>(
            aggb, hin, Wl + (size_t)i * F * F, bl + (size_t)i * F,
            Wr + (size_t)i * F * F, hout, sum, sumsq);

        bn_prep<<<1, 128, 0, stream>>>(sum, sumsq, gamma + (size_t)i * F, beta + (size_t)i * F,
                                       scale, shift);
        bn_apply<<<(N_NODES * (F / 4) + 255) / 256, 256, 0, stream>>>(hout, scale, shift);

        hin = hout;
    }
}

// Round 2
// 846.135 us; speedup vs baseline: 1.3719x; 1.3719x over previous
//
#include <hip/hip_runtime.h>
#include <hip/hip_bf16.h>

#define N_NODES 50000
#define N_EDGES 800000
#define F 128
#define BN_EPS 1e-5f
#define SLOPE 0.01f

typedef __attribute__((ext_vector_type(8))) __bf16 bf16x8_t;
typedef __attribute__((ext_vector_type(8))) unsigned short u16x8_t;
typedef __attribute__((ext_vector_type(4))) float f32x4_t;

__device__ __forceinline__ unsigned short f2b(float f) {
    unsigned int u = __float_as_uint(f);
    unsigned int r = (u + 0x7fffu + ((u >> 16) & 1u)) >> 16;  // RNE
    return (unsigned short)r;
}
__device__ __forceinline__ float b2f_lo(unsigned int v) { return __uint_as_float(v << 16); }
__device__ __forceinline__ float b2f_hi(unsigned int v) { return __uint_as_float(v & 0xffff0000u); }

// ---------------- CSR build (once per call, reused across 4 layers) ----------------

__global__ void hist_kernel(const int* __restrict__ dst, int* __restrict__ deg) {
    int e = blockIdx.x * blockDim.x + threadIdx.x;
    if (e < N_EDGES) atomicAdd(&deg[dst[e]], 1);
}

__global__ __launch_bounds__(1024) void scan_kernel(const int* __restrict__ deg,
                                                    int* __restrict__ row_off,
                                                    float* __restrict__ inv_deg) {
    __shared__ int part[1024];
    const int t = threadIdx.x;
    const int CH = (N_NODES + 1023) / 1024;  // 49
    int beg = t * CH;
    int end = beg + CH; if (end > N_NODES) end = N_NODES;
    if (beg > N_NODES) beg = N_NODES;
    int s = 0;
    for (int i = beg; i < end; ++i) s += deg[i];
    part[t] = s;
    const int own = s;
    __syncthreads();
    for (int off = 1; off < 1024; off <<= 1) {
        int v = 0;
        if (t >= off) v = part[t - off];
        __syncthreads();
        part[t] += v;
        __syncthreads();
    }
    int run = part[t] - own;
    for (int i = beg; i < end; ++i) {
        row_off[i] = run;
        int d = deg[i];
        inv_deg[i] = (d > 0) ? (1.0f / (float)d) : 0.0f;
        run += d;
    }
    if (t == 1023) row_off[N_NODES] = part[1023];
}

__global__ void fill_kernel(const int* __restrict__ src, const int* __restrict__ dst,
                            const int* __restrict__ row_off, int* __restrict__ cursor,
                            int* __restrict__ csr_src) {
    int e = blockIdx.x * blockDim.x + threadIdx.x;
    if (e < N_EDGES) {
        int d = dst[e];
        int pos = atomicAdd(&cursor[d], 1);
        csr_src[row_off[d] + pos] = src[e];
    }
}

// ---------------- prep: fp32 -> bf16 conversions ----------------

__global__ __launch_bounds__(256) void f2b_kernel(const float* __restrict__ in,
                                                  unsigned short* __restrict__ out) {
    long i = (long)blockIdx.x * blockDim.x + threadIdx.x;  // float4 index
    if (i >= (long)N_NODES * (F / 4)) return;
    float4 v = ((const float4*)in)[i];
    ushort4 o;
    o.x = f2b(v.x); o.y = f2b(v.y); o.z = f2b(v.z); o.w = f2b(v.w);
    ((ushort4*)out)[i] = o;
}

// Wt[i][n][k] (k: 0..127 from Wl[i][k][n], 128..255 from Wr[i][k-128][n])
__global__ __launch_bounds__(256) void wprep_kernel(const float* __restrict__ Wl,
                                                    const float* __restrict__ Wr,
                                                    unsigned short* __restrict__ Wt) {
    int idx = blockIdx.x * blockDim.x + threadIdx.x;  // 4*128*256 = 131072
    if (idx >= 4 * F * 256) return;
    int k = idx & 255;
    int n = (idx >> 8) & 127;
    int i = idx >> 15;
    float v = (k < F) ? Wl[((long)i * F + k) * F + n] : Wr[((long)i * F + (k - F)) * F + n];
    Wt[idx] = f2b(v);
}

// ---------------- per-layer kernels ----------------

// one wave per node; lane holds 2 features (1 uint = 2 bf16); fp32 accumulate
__global__ __launch_bounds__(256) void agg_kernel(const unsigned short* __restrict__ h,
                                                  const int* __restrict__ row_off,
                                                  const int* __restrict__ csr_src,
                                                  const float* __restrict__ inv_deg,
                                                  unsigned short* __restrict__ agg) {
    int node = (int)((blockIdx.x * (unsigned)blockDim.x + threadIdx.x) >> 6);
    int lane = threadIdx.x & 63;
    if (node >= N_NODES) return;
    int beg = row_off[node], end = row_off[node + 1];
    float ax = 0.f, ay = 0.f;
    for (int e = beg; e < end; ++e) {
        int s = csr_src[e];
        unsigned int v = *(const unsigned int*)(h + (long)s * F + lane * 2);
        ax += b2f_lo(v);
        ay += b2f_hi(v);
    }
    float inv = inv_deg[node];
    unsigned int o = (unsigned int)f2b(ax * inv) | ((unsigned int)f2b(ay * inv) << 16);
    *(unsigned int*)(agg + (long)node * F + lane * 2) = o;
}

// MFMA GEMM: P = leaky( [agg|hin](M x 256) @ Wt^T + bl ), plus BN column sums.
// block = 256 threads = 4 waves; wave handles 16 rows x 128 cols.
__global__ __launch_bounds__(256) void gemm_mfma(const unsigned short* __restrict__ aggb,
                                                 const unsigned short* __restrict__ hin,
                                                 const unsigned short* __restrict__ Wt,
                                                 const float* __restrict__ bl,
                                                 float* __restrict__ P,
                                                 float* __restrict__ sum,
                                                 float* __restrict__ sumsq) {
    __shared__ float lsum[4][F];
    __shared__ float lsq[4][F];
    const int tid = threadIdx.x;
    const int wave = tid >> 6, lane = tid & 63;
    const int m = lane & 15, q = lane >> 4;
    const int rbase = blockIdx.x * 64 + wave * 16;
    const int arow = rbase + m;
    const bool aval = arow < N_NODES;
    const unsigned short* ap = aggb + (long)arow * F + q * 8;
    const unsigned short* hp = hin + (long)arow * F + q * 8;
    const unsigned short* wb = Wt + q * 8 + m * 256;

    f32x4_t acc[8];
#pragma unroll
    for (int nt = 0; nt < 8; ++nt) acc[nt] = (f32x4_t){0.f, 0.f, 0.f, 0.f};

#pragma unroll
    for (int ks = 0; ks < 8; ++ks) {
        const int k0 = ks * 32;
        u16x8_t av = (u16x8_t)0;
        if (aval) av = *(const u16x8_t*)(ks < 4 ? (ap + k0) : (hp + (k0 - F)));
        bf16x8_t af = __builtin_bit_cast(bf16x8_t, av);
#pragma unroll
        for (int nt = 0; nt < 8; ++nt) {
            u16x8_t bv = *(const u16x8_t*)(wb + (long)nt * 16 * 256 + k0);
            bf16x8_t bf = __builtin_bit_cast(bf16x8_t, bv);
            acc[nt] = __builtin_amdgcn_mfma_f32_16x16x32_bf16(af, bf, acc[nt], 0, 0, 0);
        }
    }

    // epilogue: lane holds D[row = rbase + q*4 + r][col = nt*16 + m]
    float cs[8], cq[8];
    const int rw = rbase + q * 4;
#pragma unroll
    for (int nt = 0; nt < 8; ++nt) {
        cs[nt] = 0.f; cq[nt] = 0.f;
        const int c = nt * 16 + m;
        const float b = bl[c];
#pragma unroll
        for (int r = 0; r < 4; ++r) {
            const int grow = rw + r;
            if (grow < N_NODES) {
                float v = acc[nt][r] + b;
                v = (v >= 0.f) ? v : SLOPE * v;
                P[(long)grow * F + c] = v;
                cs[nt] += v;
                cq[nt] += v * v;
            }
        }
    }
    // reduce over the 4 row-quads (lanes differing in bits 4,5)
#pragma unroll
    for (int nt = 0; nt < 8; ++nt) {
        cs[nt] += __shfl_xor(cs[nt], 16);
        cs[nt] += __shfl_xor(cs[nt], 32);
        cq[nt] += __shfl_xor(cq[nt], 16);
        cq[nt] += __shfl_xor(cq[nt], 32);
    }
    if (lane < 16) {
#pragma unroll
        for (int nt = 0; nt < 8; ++nt) {
            lsum[wave][nt * 16 + m] = cs[nt];
            lsq[wave][nt * 16 + m] = cq[nt];
        }
    }
    __syncthreads();
    if (tid < F) {
        float s = 0.f, s2 = 0.f;
#pragma unroll
        for (int w = 0; w < 4; ++w) {
            s += lsum[w][tid];
            s2 += lsq[w][tid];
        }
        atomicAdd(&sum[tid], s);
        atomicAdd(&sumsq[tid], s2);
    }
}

__global__ void bn_prep(const float* __restrict__ sum, const float* __restrict__ sumsq,
                        const float* __restrict__ gamma, const float* __restrict__ beta,
                        float* __restrict__ scale, float* __restrict__ shift) {
    int j = threadIdx.x;
    if (j < F) {
        const float inv_n = 1.0f / (float)N_NODES;
        float mu = sum[j] * inv_n;
        float var = sumsq[j] * inv_n - mu * mu;
        float scl = gamma[j] * rsqrtf(var + BN_EPS);
        scale[j] = scl;
        shift[j] = beta[j] - mu * scl;
    }
}

// mode 0: write bf16 to outb (next layer input). mode 1: write fp32 in-place to P.
__global__ __launch_bounds__(256) void bn_apply(float* __restrict__ P,
                                                unsigned short* __restrict__ outb,
                                                const float* __restrict__ scale,
                                                const float* __restrict__ shift,
                                                int mode) {
    long i = (long)blockIdx.x * blockDim.x + threadIdx.x;  // float4 index
    if (i >= (long)N_NODES * (F / 4)) return;
    const int c4 = (int)(i & 31);
    float4 v = ((float4*)P)[i];
    const float4 sc = ((const float4*)scale)[c4];
    const float4 sh = ((const float4*)shift)[c4];
    v.x = v.x * sc.x + sh.x;
    v.y = v.y * sc.y + sh.y;
    v.z = v.z * sc.z + sh.z;
    v.w = v.w * sc.w + sh.w;
    if (mode) {
        ((float4*)P)[i] = v;
    } else {
        ushort4 o;
        o.x = f2b(v.x); o.y = f2b(v.y); o.z = f2b(v.z); o.w = f2b(v.w);
        ((ushort4*)outb)[i] = o;
    }
}

// ---------------- launch ----------------

extern "C" void kernel_launch(void* const* d_in, const int* in_sizes, int n_in,
                              void* d_out, int out_size, void* d_ws, size_t ws_size,
                              hipStream_t stream) {
    const float* x     = (const float*)d_in[0];
    const int*   ei    = (const int*)d_in[1];
    const float* Wl    = (const float*)d_in[2];
    const float* bl    = (const float*)d_in[3];
    const float* Wr    = (const float*)d_in[4];
    const float* gamma = (const float*)d_in[5];
    const float* beta  = (const float*)d_in[6];
    float* out = (float*)d_out;

    const int* src = ei;
    const int* dst = ei + N_EDGES;

    char* w = (char*)d_ws;
    auto alloc = [&](size_t bytes) -> char* {
        char* p = w;
        w += (bytes + 255) & ~(size_t)255;
        return p;
    };
    unsigned short* hbA  = (unsigned short*)alloc((size_t)N_NODES * F * 2);
    unsigned short* hbB  = (unsigned short*)alloc((size_t)N_NODES * F * 2);
    unsigned short* aggb = (unsigned short*)alloc((size_t)N_NODES * F * 2);
    unsigned short* Wt   = (unsigned short*)alloc((size_t)4 * F * 256 * 2);
    int*   deg     = (int*)alloc((size_t)N_NODES * 4);
    int*   row_off = (int*)alloc((size_t)(N_NODES + 1) * 4);
    int*   cursor  = (int*)alloc((size_t)N_NODES * 4);
    int*   csr_src = (int*)alloc((size_t)N_EDGES * 4);
    float* inv_deg = (float*)alloc((size_t)N_NODES * 4);
    float* sum     = (float*)alloc(F * 4);
    float* sumsq   = (float*)alloc(F * 4);
    float* scale   = (float*)alloc(F * 4);
    float* shift   = (float*)alloc(F * 4);

    hipMemsetAsync(deg, 0, (size_t)N_NODES * 4, stream);
    hipMemsetAsync(cursor, 0, (size_t)N_NODES * 4, stream);

    hist_kernel<<<(N_EDGES + 255) / 256, 256, 0, stream>>>(dst, deg);
    scan_kernel<<<1, 1024, 0, stream>>>(deg, row_off, inv_deg);
    fill_kernel<<<(N_EDGES + 255) / 256, 256, 0, stream>>>(src, dst, row_off, cursor, csr_src);

    const int n4 = N_NODES * (F / 4);
    f2b_kernel<<<(n4 + 255) / 256, 256, 0, stream>>>(x, hbA);
    wprep_kernel<<<(4 * F * 256 + 255) / 256, 256, 0, stream>>>(Wl, Wr, Wt);

    unsigned short* hin = hbA;
    unsigned short* hnext = hbB;
    for (int i = 0; i < 4; ++i) {
        agg_kernel<<<(N_NODES + 3) / 4, 256, 0, stream>>>(hin, row_off, csr_src, inv_deg, aggb);

        hipMemsetAsync(sum, 0, F * 4, stream);
        hipMemsetAsync(sumsq, 0, F * 4, stream);

        gemm_mfma<<<(N_NODES + 63) / 64, 256, 0, stream>>>(
            aggb, hin, Wt + (size_t)i * F * 256, bl + (size_t)i * F, out, sum, sumsq);

        bn_prep<<<1, 128, 0, stream>>>(sum, sumsq, gamma + (size_t)i * F, beta + (size_t)i * F,
                                       scale, shift);
        bn_apply<<<(n4 + 255) / 256, 256, 0, stream>>>(out, hnext, scale, shift, (i == 3) ? 1 : 0);

        unsigned short* t = hin; hin = hnext; hnext = t;
    }
}

// Round 3
// 763.997 us; speedup vs baseline: 1.5193x; 1.1075x over previous
//
#include <hip/hip_runtime.h>
#include <hip/hip_bf16.h>

#define N_NODES 50000
#define N_EDGES 800000
#define F 128
#define BN_EPS 1e-5f
#define SLOPE 0.01f

typedef __attribute__((ext_vector_type(8))) __bf16 bf16x8_t;
typedef __attribute__((ext_vector_type(8))) unsigned short u16x8_t;
typedef __attribute__((ext_vector_type(4))) float f32x4_t;

__device__ __forceinline__ unsigned short f2b(float f) {
    unsigned int u = __float_as_uint(f);
    unsigned int r = (u + 0x7fffu + ((u >> 16) & 1u)) >> 16;  // RNE
    return (unsigned short)r;
}
__device__ __forceinline__ float b2f_lo(unsigned int v) { return __uint_as_float(v << 16); }
__device__ __forceinline__ float b2f_hi(unsigned int v) { return __uint_as_float(v & 0xffff0000u); }

// ---------------- CSR build (once per call, reused across 4 layers) ----------------

__global__ void hist_kernel(const int* __restrict__ dst, int* __restrict__ deg) {
    int e = blockIdx.x * blockDim.x + threadIdx.x;
    if (e < N_EDGES) atomicAdd(&deg[dst[e]], 1);
}

// parallel CSR range allocation: ranges need not be monotonic in node index.
// wave-level inclusive scan of deg, one atomicAdd per wave on a global counter.
__global__ __launch_bounds__(256) void alloc_kernel(const int* __restrict__ deg,
                                                    int* __restrict__ row_start,
                                                    int* __restrict__ cursor,
                                                    float* __restrict__ inv_deg,
                                                    int* __restrict__ counter) {
    int i = blockIdx.x * blockDim.x + threadIdx.x;
    int lane = threadIdx.x & 63;
    int d = (i < N_NODES) ? deg[i] : 0;
    int incl = d;
#pragma unroll
    for (int off = 1; off < 64; off <<= 1) {
        int v = __shfl_up(incl, off);
        if (lane >= off) incl += v;
    }
    int total = __shfl(incl, 63);
    int base = 0;
    if (lane == 63) base = atomicAdd(counter, total);
    base = __shfl(base, 63);
    if (i < N_NODES) {
        int start = base + incl - d;
        row_start[i] = start;
        cursor[i] = start;
        inv_deg[i] = (d > 0) ? (1.0f / (float)d) : 0.0f;
    }
}

__global__ void fill_kernel(const int* __restrict__ src, const int* __restrict__ dst,
                            int* __restrict__ cursor, int* __restrict__ csr_src) {
    int e = blockIdx.x * blockDim.x + threadIdx.x;
    if (e < N_EDGES) {
        int pos = atomicAdd(&cursor[dst[e]], 1);
        csr_src[pos] = src[e];
    }
}

// ---------------- prep: fp32 -> bf16 conversions ----------------

__global__ __launch_bounds__(256) void f2b_kernel(const float* __restrict__ in,
                                                  unsigned short* __restrict__ out) {
    long i = (long)blockIdx.x * blockDim.x + threadIdx.x;  // float4 index
    if (i >= (long)N_NODES * (F / 4)) return;
    float4 v = ((const float4*)in)[i];
    ushort4 o;
    o.x = f2b(v.x); o.y = f2b(v.y); o.z = f2b(v.z); o.w = f2b(v.w);
    ((ushort4*)out)[i] = o;
}

// Wt[i][n][k] (k: 0..127 from Wl[i][k][n], 128..255 from Wr[i][k-128][n])
__global__ __launch_bounds__(256) void wprep_kernel(const float* __restrict__ Wl,
                                                    const float* __restrict__ Wr,
                                                    unsigned short* __restrict__ Wt) {
    int idx = blockIdx.x * blockDim.x + threadIdx.x;  // 4*128*256 = 131072
    if (idx >= 4 * F * 256) return;
    int k = idx & 255;
    int n = (idx >> 8) & 127;
    int i = idx >> 15;
    float v = (k < F) ? Wl[((long)i * F + k) * F + n] : Wr[((long)i * F + (k - F)) * F + n];
    Wt[idx] = f2b(v);
}

// ---------------- per-layer kernels ----------------

// one wave per node; lane holds 2 features (1 uint = 2 bf16); fp32 accumulate
__global__ __launch_bounds__(256) void agg_kernel(const unsigned short* __restrict__ h,
                                                  const int* __restrict__ row_start,
                                                  const int* __restrict__ deg,
                                                  const int* __restrict__ csr_src,
                                                  const float* __restrict__ inv_deg,
                                                  unsigned short* __restrict__ agg) {
    int node = (int)((blockIdx.x * (unsigned)blockDim.x + threadIdx.x) >> 6);
    int lane = threadIdx.x & 63;
    if (node >= N_NODES) return;
    int beg = row_start[node];
    int end = beg + deg[node];
    float ax = 0.f, ay = 0.f;
    for (int e = beg; e < end; ++e) {
        int s = csr_src[e];
        unsigned int v = *(const unsigned int*)(h + (long)s * F + lane * 2);
        ax += b2f_lo(v);
        ay += b2f_hi(v);
    }
    float inv = inv_deg[node];
    unsigned int o = (unsigned int)f2b(ax * inv) | ((unsigned int)f2b(ay * inv) << 16);
    *(unsigned int*)(agg + (long)node * F + lane * 2) = o;
}

// MFMA GEMM: P = leaky( [agg|hin](M x 256) @ Wt^T + bl ), plus BN column sums.
// block = 256 threads = 4 waves; wave handles 16 rows x 128 cols.
__global__ __launch_bounds__(256) void gemm_mfma(const unsigned short* __restrict__ aggb,
                                                 const unsigned short* __restrict__ hin,
                                                 const unsigned short* __restrict__ Wt,
                                                 const float* __restrict__ bl,
                                                 float* __restrict__ P,
                                                 float* __restrict__ sum,
                                                 float* __restrict__ sumsq) {
    __shared__ float lsum[4][F];
    __shared__ float lsq[4][F];
    const int tid = threadIdx.x;
    const int wave = tid >> 6, lane = tid & 63;
    const int m = lane & 15, q = lane >> 4;
    const int rbase = blockIdx.x * 64 + wave * 16;
    const int arow = rbase + m;
    const bool aval = arow < N_NODES;
    const unsigned short* ap = aggb + (long)arow * F + q * 8;
    const unsigned short* hp = hin + (long)arow * F + q * 8;
    const unsigned short* wb = Wt + q * 8 + m * 256;

    f32x4_t acc[8];
#pragma unroll
    for (int nt = 0; nt < 8; ++nt) acc[nt] = (f32x4_t){0.f, 0.f, 0.f, 0.f};

#pragma unroll
    for (int ks = 0; ks < 8; ++ks) {
        const int k0 = ks * 32;
        u16x8_t av = (u16x8_t)0;
        if (aval) av = *(const u16x8_t*)(ks < 4 ? (ap + k0) : (hp + (k0 - F)));
        bf16x8_t af = __builtin_bit_cast(bf16x8_t, av);
#pragma unroll
        for (int nt = 0; nt < 8; ++nt) {
            u16x8_t bv = *(const u16x8_t*)(wb + (long)nt * 16 * 256 + k0);
            bf16x8_t bf = __builtin_bit_cast(bf16x8_t, bv);
            acc[nt] = __builtin_amdgcn_mfma_f32_16x16x32_bf16(af, bf, acc[nt], 0, 0, 0);
        }
    }

    // epilogue: lane holds D[row = rbase + q*4 + r][col = nt*16 + m]
    float cs[8], cq[8];
    const int rw = rbase + q * 4;
#pragma unroll
    for (int nt = 0; nt < 8; ++nt) {
        cs[nt] = 0.f; cq[nt] = 0.f;
        const int c = nt * 16 + m;
        const float b = bl[c];
#pragma unroll
        for (int r = 0; r < 4; ++r) {
            const int grow = rw + r;
            if (grow < N_NODES) {
                float v = acc[nt][r] + b;
                v = (v >= 0.f) ? v : SLOPE * v;
                P[(long)grow * F + c] = v;
                cs[nt] += v;
                cq[nt] += v * v;
            }
        }
    }
#pragma unroll
    for (int nt = 0; nt < 8; ++nt) {
        cs[nt] += __shfl_xor(cs[nt], 16);
        cs[nt] += __shfl_xor(cs[nt], 32);
        cq[nt] += __shfl_xor(cq[nt], 16);
        cq[nt] += __shfl_xor(cq[nt], 32);
    }
    if (lane < 16) {
#pragma unroll
        for (int nt = 0; nt < 8; ++nt) {
            lsum[wave][nt * 16 + m] = cs[nt];
            lsq[wave][nt * 16 + m] = cq[nt];
        }
    }
    __syncthreads();
    if (tid < F) {
        float s = 0.f, s2 = 0.f;
#pragma unroll
        for (int w = 0; w < 4; ++w) {
            s += lsum[w][tid];
            s2 += lsq[w][tid];
        }
        atomicAdd(&sum[tid], s);
        atomicAdd(&sumsq[tid], s2);
    }
}

__global__ void bn_prep(const float* __restrict__ sum, const float* __restrict__ sumsq,
                        const float* __restrict__ gamma, const float* __restrict__ beta,
                        float* __restrict__ scale, float* __restrict__ shift) {
    int j = threadIdx.x;
    if (j < F) {
        const float inv_n = 1.0f / (float)N_NODES;
        float mu = sum[j] * inv_n;
        float var = sumsq[j] * inv_n - mu * mu;
        float scl = gamma[j] * rsqrtf(var + BN_EPS);
        scale[j] = scl;
        shift[j] = beta[j] - mu * scl;
    }
}

// mode 0: write bf16 to outb (next layer input). mode 1: write fp32 in-place to P.
__global__ __launch_bounds__(256) void bn_apply(float* __restrict__ P,
                                                unsigned short* __restrict__ outb,
                                                const float* __restrict__ scale,
                                                const float* __restrict__ shift,
                                                int mode) {
    long i = (long)blockIdx.x * blockDim.x + threadIdx.x;  // float4 index
    if (i >= (long)N_NODES * (F / 4)) return;
    const int c4 = (int)(i & 31);
    float4 v = ((float4*)P)[i];
    const float4 sc = ((const float4*)scale)[c4];
    const float4 sh = ((const float4*)shift)[c4];
    v.x = v.x * sc.x + sh.x;
    v.y = v.y * sc.y + sh.y;
    v.z = v.z * sc.z + sh.z;
    v.w = v.w * sc.w + sh.w;
    if (mode) {
        ((float4*)P)[i] = v;
    } else {
        ushort4 o;
        o.x = f2b(v.x); o.y = f2b(v.y); o.z = f2b(v.z); o.w = f2b(v.w);
        ((ushort4*)outb)[i] = o;
    }
}

// ---------------- launch ----------------

extern "C" void kernel_launch(void* const* d_in, const int* in_sizes, int n_in,
                              void* d_out, int out_size, void* d_ws, size_t ws_size,
                              hipStream_t stream) {
    const float* x     = (const float*)d_in[0];
    const int*   ei    = (const int*)d_in[1];
    const float* Wl    = (const float*)d_in[2];
    const float* bl    = (const float*)d_in[3];
    const float* Wr    = (const float*)d_in[4];
    const float* gamma = (const float*)d_in[5];
    const float* beta  = (const float*)d_in[6];
    float* out = (float*)d_out;

    const int* src = ei;
    const int* dst = ei + N_EDGES;

    char* w = (char*)d_ws;
    auto alloc = [&](size_t bytes) -> char* {
        char* p = w;
        w += (bytes + 255) & ~(size_t)255;
        return p;
    };
    unsigned short* hbA   = (unsigned short*)alloc((size_t)N_NODES * F * 2);
    unsigned short* hbB   = (unsigned short*)alloc((size_t)N_NODES * F * 2);
    unsigned short* aggb  = (unsigned short*)alloc((size_t)N_NODES * F * 2);
    unsigned short* Wt    = (unsigned short*)alloc((size_t)4 * F * 256 * 2);
    int*   deg      = (int*)alloc((size_t)N_NODES * 4);
    int*   row_start= (int*)alloc((size_t)N_NODES * 4);
    int*   cursor   = (int*)alloc((size_t)N_NODES * 4);
    int*   csr_src  = (int*)alloc((size_t)N_EDGES * 4);
    float* inv_deg  = (float*)alloc((size_t)N_NODES * 4);
    float* sum      = (float*)alloc(F * 4);
    float* sumsq    = (float*)alloc(F * 4);
    float* scale    = (float*)alloc(F * 4);
    float* shift    = (float*)alloc(F * 4);
    int*   counter  = (int*)alloc(256);

    hipMemsetAsync(deg, 0, (size_t)N_NODES * 4, stream);
    hipMemsetAsync(counter, 0, 4, stream);

    hist_kernel<<<(N_EDGES + 255) / 256, 256, 0, stream>>>(dst, deg);
    alloc_kernel<<<(N_NODES + 255) / 256, 256, 0, stream>>>(deg, row_start, cursor, inv_deg,
                                                            counter);
    fill_kernel<<<(N_EDGES + 255) / 256, 256, 0, stream>>>(src, dst, cursor, csr_src);

    const int n4 = N_NODES * (F / 4);
    f2b_kernel<<<(n4 + 255) / 256, 256, 0, stream>>>(x, hbA);
    wprep_kernel<<<(4 * F * 256 + 255) / 256, 256, 0, stream>>>(Wl, Wr, Wt);

    unsigned short* hin = hbA;
    unsigned short* hnext = hbB;
    for (int i = 0; i < 4; ++i) {
        agg_kernel<<<(N_NODES + 3) / 4, 256, 0, stream>>>(hin, row_start, deg, csr_src, inv_deg,
                                                          aggb);

        hipMemsetAsync(sum, 0, F * 4, stream);
        hipMemsetAsync(sumsq, 0, F * 4, stream);

        gemm_mfma<<<(N_NODES + 63) / 64, 256, 0, stream>>>(
            aggb, hin, Wt + (size_t)i * F * 256, bl + (size_t)i * F, out, sum, sumsq);

        bn_prep<<<1, 128, 0, stream>>>(sum, sumsq, gamma + (size_t)i * F, beta + (size_t)i * F,
                                       scale, shift);
        bn_apply<<<(n4 + 255) / 256, 256, 0, stream>>>(out, hnext, scale, shift, (i == 3) ? 1 : 0);

        unsigned short* t = hin; hin = hnext; hnext = t;
    }
}

// Round 4
// 568.829 us; speedup vs baseline: 2.0406x; 1.3431x over previous
//
#include <hip/hip_runtime.h>
#include <hip/hip_bf16.h>

#define N_NODES 50000
#define N_EDGES 800000
#define F 128
#define BN_EPS 1e-5f
#define SLOPE 0.01f

typedef __attribute__((ext_vector_type(8))) __bf16 bf16x8_t;
typedef __attribute__((ext_vector_type(8))) unsigned short u16x8_t;
typedef __attribute__((ext_vector_type(4))) float f32x4_t;

__device__ __forceinline__ unsigned short f2b(float f) {
    unsigned int u = __float_as_uint(f);
    unsigned int r = (u + 0x7fffu + ((u >> 16) & 1u)) >> 16;  // RNE
    return (unsigned short)r;
}
__device__ __forceinline__ float b2f_lo(unsigned int v) { return __uint_as_float(v << 16); }
__device__ __forceinline__ float b2f_hi(unsigned int v) { return __uint_as_float(v & 0xffff0000u); }

// ---------------- CSR build (once per call, reused across 4 layers) ----------------

__global__ void hist_kernel(const int* __restrict__ dst, int* __restrict__ deg) {
    int e = blockIdx.x * blockDim.x + threadIdx.x;
    if (e < N_EDGES) atomicAdd(&deg[dst[e]], 1);
}

// parallel CSR range allocation: ranges need not be monotonic in node index.
__global__ __launch_bounds__(256) void alloc_kernel(const int* __restrict__ deg,
                                                    int* __restrict__ row_start,
                                                    int* __restrict__ cursor,
                                                    float* __restrict__ inv_deg,
                                                    int* __restrict__ counter) {
    int i = blockIdx.x * blockDim.x + threadIdx.x;
    int lane = threadIdx.x & 63;
    int d = (i < N_NODES) ? deg[i] : 0;
    int incl = d;
#pragma unroll
    for (int off = 1; off < 64; off <<= 1) {
        int v = __shfl_up(incl, off);
        if (lane >= off) incl += v;
    }
    int total = __shfl(incl, 63);
    int base = 0;
    if (lane == 63) base = atomicAdd(counter, total);
    base = __shfl(base, 63);
    if (i < N_NODES) {
        int start = base + incl - d;
        row_start[i] = start;
        cursor[i] = start;
        inv_deg[i] = (d > 0) ? (1.0f / (float)d) : 0.0f;
    }
}

__global__ void fill_kernel(const int* __restrict__ src, const int* __restrict__ dst,
                            int* __restrict__ cursor, int* __restrict__ csr_src) {
    int e = blockIdx.x * blockDim.x + threadIdx.x;
    if (e < N_EDGES) {
        int pos = atomicAdd(&cursor[dst[e]], 1);
        csr_src[pos] = src[e];
    }
}

// ---------------- prep: fp32 -> bf16 conversions ----------------

__global__ __launch_bounds__(256) void f2b_kernel(const float* __restrict__ in,
                                                  unsigned short* __restrict__ out) {
    long i = (long)blockIdx.x * blockDim.x + threadIdx.x;  // float4 index
    if (i >= (long)N_NODES * (F / 4)) return;
    float4 v = ((const float4*)in)[i];
    ushort4 o;
    o.x = f2b(v.x); o.y = f2b(v.y); o.z = f2b(v.z); o.w = f2b(v.w);
    ((ushort4*)out)[i] = o;
}

// Wt[i][n][k] (k: 0..127 from Wl[i][k][n], 128..255 from Wr[i][k-128][n])
__global__ __launch_bounds__(256) void wprep_kernel(const float* __restrict__ Wl,
                                                    const float* __restrict__ Wr,
                                                    unsigned short* __restrict__ Wt) {
    int idx = blockIdx.x * blockDim.x + threadIdx.x;  // 4*128*256 = 131072
    if (idx >= 4 * F * 256) return;
    int k = idx & 255;
    int n = (idx >> 8) & 127;
    int i = idx >> 15;
    float v = (k < F) ? Wl[((long)i * F + k) * F + n] : Wr[((long)i * F + (k - F)) * F + n];
    Wt[idx] = f2b(v);
}

// ---------------- per-layer kernels ----------------

// one wave per node; lane holds 2 features; 8-way unrolled gather for MLP.
__global__ __launch_bounds__(256) void agg_kernel(const unsigned short* __restrict__ h,
                                                  const int* __restrict__ row_start,
                                                  const int* __restrict__ deg,
                                                  const int* __restrict__ csr_src,
                                                  const float* __restrict__ inv_deg,
                                                  unsigned short* __restrict__ agg) {
    int node = (int)((blockIdx.x * (unsigned)blockDim.x + threadIdx.x) >> 6);
    int lane = threadIdx.x & 63;
    if (node >= N_NODES) return;
    const int beg = row_start[node];
    const int end = beg + deg[node];
    const unsigned short* hl = h + lane * 2;
    float ax = 0.f, ay = 0.f;
    for (int e = beg; e < end; e += 8) {
        int idx[8];
#pragma unroll
        for (int j = 0; j < 8; ++j) {
            int ee = e + j;
            idx[j] = csr_src[(ee < end) ? ee : beg];
        }
        unsigned int v[8];
#pragma unroll
        for (int j = 0; j < 8; ++j)
            v[j] = *(const unsigned int*)(hl + (long)idx[j] * F);
#pragma unroll
        for (int j = 0; j < 8; ++j) {
            unsigned int m = (e + j < end) ? v[j] : 0u;
            ax += b2f_lo(m);
            ay += b2f_hi(m);
        }
    }
    float inv = inv_deg[node];
    unsigned int o = (unsigned int)f2b(ax * inv) | ((unsigned int)f2b(ay * inv) << 16);
    *(unsigned int*)(agg + (long)node * F + lane * 2) = o;
}

// MFMA GEMM: P = leaky( [agg|hin](M x 256) @ Wt^T + bl ), plus BN column sums.
// write_bf16=1: store P as bf16 into Pb; else fp32 into Pf.
__global__ __launch_bounds__(256) void gemm_mfma(const unsigned short* __restrict__ aggb,
                                                 const unsigned short* __restrict__ hin,
                                                 const unsigned short* __restrict__ Wt,
                                                 const float* __restrict__ bl,
                                                 float* __restrict__ Pf,
                                                 unsigned short* __restrict__ Pb,
                                                 int write_bf16,
                                                 float* __restrict__ sum,
                                                 float* __restrict__ sumsq) {
    __shared__ float lsum[4][F];
    __shared__ float lsq[4][F];
    const int tid = threadIdx.x;
    const int wave = tid >> 6, lane = tid & 63;
    const int m = lane & 15, q = lane >> 4;
    const int rbase = blockIdx.x * 64 + wave * 16;
    const int arow = rbase + m;
    const bool aval = arow < N_NODES;
    const unsigned short* ap = aggb + (long)arow * F + q * 8;
    const unsigned short* hp = hin + (long)arow * F + q * 8;
    const unsigned short* wb = Wt + q * 8 + m * 256;

    f32x4_t acc[8];
#pragma unroll
    for (int nt = 0; nt < 8; ++nt) acc[nt] = (f32x4_t){0.f, 0.f, 0.f, 0.f};

#pragma unroll
    for (int ks = 0; ks < 8; ++ks) {
        const int k0 = ks * 32;
        u16x8_t av = (u16x8_t)0;
        if (aval) av = *(const u16x8_t*)(ks < 4 ? (ap + k0) : (hp + (k0 - F)));
        bf16x8_t af = __builtin_bit_cast(bf16x8_t, av);
#pragma unroll
        for (int nt = 0; nt < 8; ++nt) {
            u16x8_t bv = *(const u16x8_t*)(wb + (long)nt * 16 * 256 + k0);
            bf16x8_t bf = __builtin_bit_cast(bf16x8_t, bv);
            acc[nt] = __builtin_amdgcn_mfma_f32_16x16x32_bf16(af, bf, acc[nt], 0, 0, 0);
        }
    }

    // epilogue: lane holds D[row = rbase + q*4 + r][col = nt*16 + m]
    float cs[8], cq[8];
    const int rw = rbase + q * 4;
#pragma unroll
    for (int nt = 0; nt < 8; ++nt) {
        cs[nt] = 0.f; cq[nt] = 0.f;
        const int c = nt * 16 + m;
        const float b = bl[c];
#pragma unroll
        for (int r = 0; r < 4; ++r) {
            const int grow = rw + r;
            if (grow < N_NODES) {
                float v = acc[nt][r] + b;
                v = (v >= 0.f) ? v : SLOPE * v;
                if (write_bf16) {
                    Pb[(long)grow * F + c] = f2b(v);
                } else {
                    Pf[(long)grow * F + c] = v;
                }
                cs[nt] += v;
                cq[nt] += v * v;
            }
        }
    }
#pragma unroll
    for (int nt = 0; nt < 8; ++nt) {
        cs[nt] += __shfl_xor(cs[nt], 16);
        cs[nt] += __shfl_xor(cs[nt], 32);
        cq[nt] += __shfl_xor(cq[nt], 16);
        cq[nt] += __shfl_xor(cq[nt], 32);
    }
    if (lane < 16) {
#pragma unroll
        for (int nt = 0; nt < 8; ++nt) {
            lsum[wave][nt * 16 + m] = cs[nt];
            lsq[wave][nt * 16 + m] = cq[nt];
        }
    }
    __syncthreads();
    if (tid < F) {
        float s = 0.f, s2 = 0.f;
#pragma unroll
        for (int w = 0; w < 4; ++w) {
            s += lsum[w][tid];
            s2 += lsq[w][tid];
        }
        atomicAdd(&sum[tid], s);
        atomicAdd(&sumsq[tid], s2);
    }
}

__global__ void bn_prep(const float* __restrict__ sum, const float* __restrict__ sumsq,
                        const float* __restrict__ gamma, const float* __restrict__ beta,
                        float* __restrict__ scale, float* __restrict__ shift) {
    int j = threadIdx.x;
    if (j < F) {
        const float inv_n = 1.0f / (float)N_NODES;
        float mu = sum[j] * inv_n;
        float var = sumsq[j] * inv_n - mu * mu;
        float scl = gamma[j] * rsqrtf(var + BN_EPS);
        scale[j] = scl;
        shift[j] = beta[j] - mu * scl;
    }
}

// bf16 P -> bf16 h_next (layers 0-2): 8 features per thread
__global__ __launch_bounds__(256) void bn_apply_b(const unsigned short* __restrict__ Pb,
                                                  unsigned short* __restrict__ outb,
                                                  const float* __restrict__ scale,
                                                  const float* __restrict__ shift) {
    long i = (long)blockIdx.x * blockDim.x + threadIdx.x;  // uint4 index (8 bf16)
    if (i >= (long)N_NODES * (F / 8)) return;
    const int c8 = (int)(i & 15);  // feature block
    uint4 v = ((const uint4*)Pb)[i];
    const float4 sc0 = ((const float4*)scale)[c8 * 2];
    const float4 sc1 = ((const float4*)scale)[c8 * 2 + 1];
    const float4 sh0 = ((const float4*)shift)[c8 * 2];
    const float4 sh1 = ((const float4*)shift)[c8 * 2 + 1];
    uint4 o;
    o.x = (unsigned int)f2b(b2f_lo(v.x) * sc0.x + sh0.x) |
          ((unsigned int)f2b(b2f_hi(v.x) * sc0.y + sh0.y) << 16);
    o.y = (unsigned int)f2b(b2f_lo(v.y) * sc0.z + sh0.z) |
          ((unsigned int)f2b(b2f_hi(v.y) * sc0.w + sh0.w) << 16);
    o.z = (unsigned int)f2b(b2f_lo(v.z) * sc1.x + sh1.x) |
          ((unsigned int)f2b(b2f_hi(v.z) * sc1.y + sh1.y) << 16);
    o.w = (unsigned int)f2b(b2f_lo(v.z ^ (v.z ^ v.w)) * sc1.z + sh1.z) |
          ((unsigned int)f2b(b2f_hi(v.w) * sc1.w + sh1.w) << 16);
    ((uint4*)outb)[i] = o;
}

// fp32 P -> fp32 out, in place (final layer)
__global__ __launch_bounds__(256) void bn_apply_f(float* __restrict__ P,
                                                  const float* __restrict__ scale,
                                                  const float* __restrict__ shift) {
    long i = (long)blockIdx.x * blockDim.x + threadIdx.x;  // float4 index
    if (i >= (long)N_NODES * (F / 4)) return;
    const int c4 = (int)(i & 31);
    float4 v = ((float4*)P)[i];
    const float4 sc = ((const float4*)scale)[c4];
    const float4 sh = ((const float4*)shift)[c4];
    v.x = v.x * sc.x + sh.x;
    v.y = v.y * sc.y + sh.y;
    v.z = v.z * sc.z + sh.z;
    v.w = v.w * sc.w + sh.w;
    ((float4*)P)[i] = v;
}

// ---------------- launch ----------------

extern "C" void kernel_launch(void* const* d_in, const int* in_sizes, int n_in,
                              void* d_out, int out_size, void* d_ws, size_t ws_size,
                              hipStream_t stream) {
    const float* x     = (const float*)d_in[0];
    const int*   ei    = (const int*)d_in[1];
    const float* Wl    = (const float*)d_in[2];
    const float* bl    = (const float*)d_in[3];
    const float* Wr    = (const float*)d_in[4];
    const float* gamma = (const float*)d_in[5];
    const float* beta  = (const float*)d_in[6];
    float* out = (float*)d_out;

    const int* src = ei;
    const int* dst = ei + N_EDGES;

    char* w = (char*)d_ws;
    auto alloc = [&](size_t bytes) -> char* {
        char* p = w;
        w += (bytes + 255) & ~(size_t)255;
        return p;
    };
    unsigned short* hbA   = (unsigned short*)alloc((size_t)N_NODES * F * 2);
    unsigned short* hbB   = (unsigned short*)alloc((size_t)N_NODES * F * 2);
    unsigned short* aggb  = (unsigned short*)alloc((size_t)N_NODES * F * 2);
    unsigned short* Wt    = (unsigned short*)alloc((size_t)4 * F * 256 * 2);
    int*   deg      = (int*)alloc((size_t)N_NODES * 4);
    int*   row_start= (int*)alloc((size_t)N_NODES * 4);
    int*   cursor   = (int*)alloc((size_t)N_NODES * 4);
    int*   csr_src  = (int*)alloc((size_t)N_EDGES * 4);
    float* inv_deg  = (float*)alloc((size_t)N_NODES * 4);
    float* sum      = (float*)alloc(F * 4);
    float* sumsq    = (float*)alloc(F * 4);
    float* scale    = (float*)alloc(F * 4);
    float* shift    = (float*)alloc(F * 4);
    int*   counter  = (int*)alloc(256);

    hipMemsetAsync(deg, 0, (size_t)N_NODES * 4, stream);
    hipMemsetAsync(counter, 0, 4, stream);

    hist_kernel<<<(N_EDGES + 255) / 256, 256, 0, stream>>>(dst, deg);
    alloc_kernel<<<(N_NODES + 255) / 256, 256, 0, stream>>>(deg, row_start, cursor, inv_deg,
                                                            counter);
    fill_kernel<<<(N_EDGES + 255) / 256, 256, 0, stream>>>(src, dst, cursor, csr_src);

    const int n4 = N_NODES * (F / 4);
    const int n8 = N_NODES * (F / 8);
    f2b_kernel<<<(n4 + 255) / 256, 256, 0, stream>>>(x, hbA);
    wprep_kernel<<<(4 * F * 256 + 255) / 256, 256, 0, stream>>>(Wl, Wr, Wt);

    unsigned short* Pb = (unsigned short*)out;  // reuse d_out as bf16 scratch (layers 0-2)

    unsigned short* hin = hbA;
    unsigned short* hnext = hbB;
    for (int i = 0; i < 4; ++i) {
        agg_kernel<<<(N_NODES + 3) / 4, 256, 0, stream>>>(hin, row_start, deg, csr_src, inv_deg,
                                                          aggb);

        hipMemsetAsync(sum, 0, F * 4, stream);
        hipMemsetAsync(sumsq, 0, F * 4, stream);

        const int last = (i == 3);
        gemm_mfma<<<(N_NODES + 63) / 64, 256, 0, stream>>>(
            aggb, hin, Wt + (size_t)i * F * 256, bl + (size_t)i * F,
            out, Pb, last ? 0 : 1, sum, sumsq);

        bn_prep<<<1, 128, 0, stream>>>(sum, sumsq, gamma + (size_t)i * F, beta + (size_t)i * F,
                                       scale, shift);
        if (last) {
            bn_apply_f<<<(n4 + 255) / 256, 256, 0, stream>>>(out, scale, shift);
        } else {
            bn_apply_b<<<(n8 + 255) / 256, 256, 0, stream>>>(Pb, hnext, scale, shift);
        }

        unsigned short* t = hin; hin = hnext; hnext = t;
    }
}